// Round 9
// baseline (2339.974 us; speedup 1.0000x reference)
//
#include <hip/hip_runtime.h>
#include <math.h>

typedef _Float16 f16;
typedef _Float16 f16x8 __attribute__((ext_vector_type(8)));
typedef float f32x4 __attribute__((ext_vector_type(4)));
typedef unsigned long long u64;
typedef unsigned u32;

union U32H2 { unsigned u; f16 h[2]; };
union UV4H8 { uint4 u; f16x8 h; f16 e[8]; };

#define LN_EPS 1e-5f

// ---- cache-bypassing (L3-coherent) 8-byte atomics, relaxed agent scope ----
__device__ __forceinline__ void st_u64g(u64* p, u64 v) {
    __hip_atomic_store(p, v, __ATOMIC_RELAXED, __HIP_MEMORY_SCOPE_AGENT);
}
__device__ __forceinline__ u64 ld_u64g(const u64* p) {
    return __hip_atomic_load(p, __ATOMIC_RELAXED, __HIP_MEMORY_SCOPE_AGENT);
}

// ============================================================================
// init: zero tagged-exchange buffer (every launch — replay safety)
// ============================================================================
__global__ __launch_bounds__(256) void init_ex(u64* p, int n) {
    const int i = blockIdx.x * 256 + threadIdx.x;
    if (i < n) p[i] = 0ull;
}

// ============================================================================
// Phase 0a: pack h-part weights, GAMMA-FOLDED, into MFMA B-fragment order.
//   W'[col][k] = W[col][k] * gamma[k]
//   col = (tile%32)*16 + (lane&15),  k = kf*32 + (lane>>4)*8 + j
// tiles 0..31 = a-gate, 32..63 = g-gate.
// ============================================================================
__global__ __launch_bounds__(256) void pack_wfrags(
    const float* __restrict__ Wa, const float* __restrict__ Wg,
    const float* __restrict__ gamma, uint4* __restrict__ WP)
{
    const int t = blockIdx.x * 256 + threadIdx.x;   // 0..65535
    const int lane = t & 63;
    const int kf = (t >> 6) & 15;
    const int tile = t >> 10;
    const float* W = (tile < 32) ? Wa : Wg;
    const int col = (tile & 31) * 16 + (lane & 15);
    const int k0 = kf * 32 + (lane >> 4) * 8;
    const float* src = W + (size_t)col * 1024 + k0;
    UV4H8 u;
#pragma unroll
    for (int j = 0; j < 8; ++j) u.e[j] = (f16)(src[j] * gamma[k0 + j]);
    WP[t] = u.u;
}

// ============================================================================
// Phase 0b: fold constants:
//   Cvec[0][o]=Wa[o]·beta  Cvec[1][o]=Wa[o]·gamma  Cvec[2][o]=Wg[o]·beta
//   Cvec[3][o]=Wg[o]·gamma   (h-part k<512, fp32)
// ============================================================================
__global__ __launch_bounds__(64) void precompute_consts(
    const float* __restrict__ Wa, const float* __restrict__ Wg,
    const float* __restrict__ gamma, const float* __restrict__ beta,
    float* __restrict__ Cvec)
{
    const int o = blockIdx.x;
    const int l = threadIdx.x;
    const float* wa = Wa + (size_t)o * 1024;
    const float* wg = Wg + (size_t)o * 1024;
    float ca = 0.f, ga = 0.f, cg = 0.f, gg = 0.f;
    for (int k = l; k < 512; k += 64) {
        const float bk = beta[k], gk = gamma[k], a = wa[k], g = wg[k];
        ca += a * bk; ga += a * gk; cg += g * bk; gg += g * gk;
    }
#pragma unroll
    for (int m = 1; m < 64; m <<= 1) {
        ca += __shfl_xor(ca, m); ga += __shfl_xor(ga, m);
        cg += __shfl_xor(cg, m); gg += __shfl_xor(gg, m);
    }
    if (l == 0) {
        Cvec[o] = ca; Cvec[512 + o] = ga; Cvec[1024 + o] = cg; Cvec[1536 + o] = gg;
    }
}

// ============================================================================
// Phase 1: precompute P = X @ Wx^T + bias (x-part = cols 512..1023 of W).
// Pa -> d_out (fp32); Pg -> ws as f16. (unchanged — verified)
// ============================================================================
__global__ __launch_bounds__(256) void precompute_gemm(
    const float* __restrict__ X, const float* __restrict__ Wa,
    const float* __restrict__ Wg, const float* __restrict__ ba,
    const float* __restrict__ bg, float* __restrict__ Pa,
    f16* __restrict__ Pgh)
{
    __shared__ float As[16][132];
    __shared__ float Bs[16][132];
    const int bid = blockIdx.x;
    const int bn = bid & 7;
    const int bm = bid >> 3;
    const int tid = threadIdx.x;
    const int tx = tid & 15;
    const int ty = tid >> 4;

    const int m0 = bm * 128;
    const int n0 = bn * 128;

    const float* Wbase = (n0 < 512) ? (Wa + (size_t)n0 * 1024 + 512)
                                    : (Wg + (size_t)(n0 - 512) * 1024 + 512);

    float acc[8][8];
#pragma unroll
    for (int i = 0; i < 8; ++i)
#pragma unroll
        for (int j = 0; j < 8; ++j) acc[i][j] = 0.f;

    for (int k0 = 0; k0 < 512; k0 += 16) {
        {
            int idx = tid;
#pragma unroll
            for (int rep = 0; rep < 2; ++rep) {
                const int mrow = idx >> 2;
                const int kq = (idx & 3) * 4;
                const float4 v = *(const float4*)(X + (size_t)(m0 + mrow) * 512 + k0 + kq);
                As[kq + 0][mrow] = v.x;
                As[kq + 1][mrow] = v.y;
                As[kq + 2][mrow] = v.z;
                As[kq + 3][mrow] = v.w;
                idx += 256;
            }
        }
        {
            int idx = tid;
#pragma unroll
            for (int rep = 0; rep < 2; ++rep) {
                const int jrow = idx >> 2;
                const int kq = (idx & 3) * 4;
                const float4 v = *(const float4*)(Wbase + (size_t)jrow * 1024 + k0 + kq);
                Bs[kq + 0][jrow] = v.x;
                Bs[kq + 1][jrow] = v.y;
                Bs[kq + 2][jrow] = v.z;
                Bs[kq + 3][jrow] = v.w;
                idx += 256;
            }
        }
        __syncthreads();
#pragma unroll
        for (int kk = 0; kk < 16; ++kk) {
            float a[8], b[8];
            const float4 a0 = *(const float4*)&As[kk][ty * 8];
            const float4 a1 = *(const float4*)&As[kk][ty * 8 + 4];
            const float4 b0 = *(const float4*)&Bs[kk][tx * 8];
            const float4 b1 = *(const float4*)&Bs[kk][tx * 8 + 4];
            a[0] = a0.x; a[1] = a0.y; a[2] = a0.z; a[3] = a0.w;
            a[4] = a1.x; a[5] = a1.y; a[6] = a1.z; a[7] = a1.w;
            b[0] = b0.x; b[1] = b0.y; b[2] = b0.z; b[3] = b0.w;
            b[4] = b1.x; b[5] = b1.y; b[6] = b1.z; b[7] = b1.w;
#pragma unroll
            for (int i = 0; i < 8; ++i)
#pragma unroll
                for (int j = 0; j < 8; ++j) acc[i][j] += a[i] * b[j];
        }
        __syncthreads();
    }

    const bool isA = (n0 < 512);
#pragma unroll
    for (int i = 0; i < 8; ++i) {
        const int m = m0 + ty * 8 + i;
        const int jbase = n0 + tx * 8;
#pragma unroll
        for (int j = 0; j < 8; ++j) {
            const int jg = jbase + j;
            const float bia = isA ? ba[jg] : bg[jg - 512];
            const float v = acc[i][j] + bia;
            if (isA) Pa[(size_t)m * 512 + jg] = v;
            else     Pgh[(size_t)m * 512 + (jg - 512)] = (f16)v;
        }
    }
}

// ============================================================================
// Phase 2: recurrent scan, v9 — EXACT round-6 arithmetic/MFMA path
// (Bf[16] per wave, 2-chain accumulate, Dx[16][132], scalar blend reads),
// plus only: (b) own col-slice substituted from registers (never polled),
// (c) trailing barrier removed (sync1/sync2 order all LDS hazards).
// Exchange: agent-scope self-tagged u64 = (t+1)<<32 | 2xf16, parity dbuf.
// ============================================================================
__global__ __launch_bounds__(512, 1) void scan9(
    const uint4* __restrict__ WP, const float* __restrict__ gamma,
    const float* __restrict__ beta, const float* __restrict__ Cvec,
    float* po, const f16* __restrict__ Pgh,
    u64* __restrict__ THex)   // [2][8][16][256] tagged
{
    __shared__ f16 hn[16][512];      // raw h̃, XOR-swizzled
    __shared__ float Dx[16][132];    // MFMA D exchange

    const int tid = threadIdx.x;
    const int wv = tid >> 6, lane = tid & 63;
    const int bid = blockIdx.x;
    const int rg = bid >> 3, cb = bid & 7;
    const int c0 = cb * 64, r0 = rg * 16;

    // ---- static weight fragments (gamma-folded) into registers ----
    const int tile = (wv < 4) ? (cb * 4 + wv) : (32 + cb * 4 + (wv - 4));
    f16x8 Bf[16];
#pragma unroll
    for (int kf = 0; kf < 16; ++kf) {
        UV4H8 uu; uu.u = WP[(size_t)(tile * 16 + kf) * 64 + lane];
        Bf[kf] = uu.h;
    }

    for (int i = tid; i < 16 * 256; i += 512) ((unsigned*)hn)[i] = 0u;

    const int rb = tid >> 5, u = tid & 31;
    const int col0 = c0 + 2 * u;
    const float Ca0 = Cvec[col0],        Ca1 = Cvec[col0 + 1];
    const float Ga0 = Cvec[512 + col0],  Ga1 = Cvec[512 + col0 + 1];
    const float Cg0 = Cvec[1024 + col0], Cg1 = Cvec[1024 + col0 + 1];
    const float Gg0 = Cvec[1536 + col0], Gg1 = Cvec[1536 + col0 + 1];
    const float gm0 = gamma[col0], gm1 = gamma[col0 + 1];
    const float bt0 = beta[col0],  bt1 = beta[col0 + 1];

    const int arow = lane & 15;
    const int hi16 = (lane >> 4) * 16;
    const int swzr = (arow & 7) << 4;
    const int swzw = (rb & 7) << 4;
    const char* hrow_r = (const char*)&hn[arow][0];
    char* hrow_w = (char*)&hn[rb][0];
    const int dr = (lane >> 4) * 4;
    const int dc = wv * 16 + (lane & 15);
    const size_t row = (size_t)(r0 + rb);

    // publish slot: row*256 + cb*32 + u ; poll base: row*256 + u (+i*32)
    u64* pub0 = THex + ((size_t)0 * 8 + rg) * 4096 + (size_t)rb * 256 + cb * 32 + u;
    u64* pub1 = THex + ((size_t)1 * 8 + rg) * 4096 + (size_t)rb * 256 + cb * 32 + u;
    const u64* pol0 = THex + ((size_t)0 * 8 + rg) * 4096 + (size_t)rb * 256 + u;
    const u64* pol1 = THex + ((size_t)1 * 8 + rg) * 4096 + (size_t)rb * 256 + u;
    const unsigned ownbit = 1u << cb;

    float ht0, ht1;
    u32 own32;
    // ---- t = 0: h_prev = 0 -> a = pa, g = pg ----
    {
        const size_t orow = (row * 512 + 0) * 512 + col0;
        const float2 pa = *(const float2*)(po + orow);
        U32H2 pg; pg.u = *(const unsigned*)(Pgh + orow);
        const float a0 = pa.x, a1 = pa.y;
        const float g0 = (float)pg.h[0], g1 = (float)pg.h[1];
        const float al0 = 1.f / (1.f + __expf(-g0));
        const float al1 = 1.f / (1.f + __expf(-g1));
        const float ac0 = fminf(fmaxf(a0, -15.f), 15.f);
        const float ac1 = fminf(fmaxf(a1, -15.f), 15.f);
        const float e0 = __expf(2.f * ac0), e1 = __expf(2.f * ac1);
        const float th0 = (e0 - 1.f) / (e0 + 1.f);
        const float th1 = (e1 - 1.f) / (e1 + 1.f);
        ht0 = al0 * (th0 - a0) + a0;
        ht1 = al1 * (th1 - a1) + a1;
        U32H2 hw; hw.h[0] = (f16)ht0; hw.h[1] = (f16)ht1;
        own32 = hw.u;
        st_u64g(pub0, ((u64)1u << 32) | (u64)own32);
    }

    for (int t = 1; t < 512; ++t) {
        const unsigned tg = (unsigned)t;
        const u64* hp = ((t - 1) & 1) ? pol1 : pol0;
        const size_t orow = (row * 512 + (size_t)t) * 512 + col0;
        const float2 pa = *(const float2*)(po + orow);
        U32H2 pg; pg.u = *(const unsigned*)(Pgh + orow);

        // ---- coalesced poll of the 7 REMOTE chunks (own slice from regs) ----
        u64 v[8];
        unsigned miss = 0xFFu & ~ownbit;
        while (miss) {
#pragma unroll
            for (int i = 0; i < 8; ++i)
                if (miss & (1u << i)) v[i] = ld_u64g(hp + i * 32);
#pragma unroll
            for (int i = 0; i < 8; ++i)
                if ((miss & (1u << i)) && (unsigned)(v[i] >> 32) == tg)
                    miss &= ~(1u << i);
        }
        v[cb] = (u64)own32;

        // ---- local LN stats of h̃_{t-1} + swizzled LDS rebuild ----
        float s1 = 0.f, s2 = 0.f;
#pragma unroll
        for (int i = 0; i < 8; ++i) {
            U32H2 hh; hh.u = (unsigned)v[i];
            const float x0 = (float)hh.h[0], x1 = (float)hh.h[1];
            s1 += x0 + x1; s2 += x0 * x0 + x1 * x1;
            *(u32*)(hrow_w + ((128 * i + 4 * u) ^ swzw)) = (unsigned)v[i];
        }
#pragma unroll
        for (int m = 1; m < 32; m <<= 1) { s1 += __shfl_xor(s1, m); s2 += __shfl_xor(s2, m); }
        const float mu = s1 * (1.f / 512.f);
        const float var = s2 * (1.f / 512.f) - mu * mu;
        const float rs = rsqrtf(fmaxf(var, 0.f) + LN_EPS);
        const float murs = mu * rs;
        __syncthreads();   // sync1: hn rebuilt

        // ---- MFMA on raw h̃ (gamma folded), 2 accumulators — ROUND-6 EXACT ----
        f32x4 acc0 = {0.f, 0.f, 0.f, 0.f};
        f32x4 acc1 = {0.f, 0.f, 0.f, 0.f};
#pragma unroll
        for (int kf = 0; kf < 8; ++kf) {
            const f16x8 Af0 = *(const f16x8*)(hrow_r + ((kf * 64 + hi16) ^ swzr));
            acc0 = __builtin_amdgcn_mfma_f32_16x16x32_f16(Af0, Bf[kf], acc0, 0, 0, 0);
            const f16x8 Af1 = *(const f16x8*)(hrow_r + (((kf + 8) * 64 + hi16) ^ swzr));
            acc1 = __builtin_amdgcn_mfma_f32_16x16x32_f16(Af1, Bf[kf + 8], acc1, 0, 0, 0);
        }
        Dx[dr + 0][dc] = acc0[0] + acc1[0];
        Dx[dr + 1][dc] = acc0[1] + acc1[1];
        Dx[dr + 2][dc] = acc0[2] + acc1[2];
        Dx[dr + 3][dc] = acc0[3] + acc1[3];
        __syncthreads();   // sync2: Dx ready

        // ---- scalar LN correction + gated blend — ROUND-6 EXACT ----
        const float a0 = rs * Dx[rb][2 * u]          - murs * Ga0 + Ca0 + pa.x;
        const float a1 = rs * Dx[rb][2 * u + 1]      - murs * Ga1 + Ca1 + pa.y;
        const float g0 = rs * Dx[rb][64 + 2 * u]     - murs * Gg0 + Cg0 + (float)pg.h[0];
        const float g1 = rs * Dx[rb][64 + 2 * u + 1] - murs * Gg1 + Cg1 + (float)pg.h[1];
        const float al0 = 1.f / (1.f + __expf(-g0));
        const float al1 = 1.f / (1.f + __expf(-g1));
        const float ac0 = fminf(fmaxf(a0, -15.f), 15.f);
        const float ac1 = fminf(fmaxf(a1, -15.f), 15.f);
        const float e0 = __expf(2.f * ac0), e1 = __expf(2.f * ac1);
        const float th0 = (e0 - 1.f) / (e0 + 1.f);
        const float th1 = (e1 - 1.f) / (e1 + 1.f);
        const float nt0 = al0 * (th0 - a0) + a0;
        const float nt1 = al1 * (th1 - a1) + a1;

        // ---- publish h̃_t FIRST (consumers' critical path) ----
        {
            U32H2 hw; hw.h[0] = (f16)nt0; hw.h[1] = (f16)nt1;
            st_u64g((t & 1) ? pub1 : pub0,
                    ((u64)(unsigned)(t + 1) << 32) | (u64)hw.u);
            po[orow - 512]     = (ht0 - mu) * rs * gm0 + bt0;
            po[orow - 512 + 1] = (ht1 - mu) * rs * gm1 + bt1;
            ht0 = nt0; ht1 = nt1; own32 = hw.u;
        }
        // no trailing barrier: rebuild(t+1) is after sync2(t) in every thread's
        // program order; MFMA reads(t) complete before any thread passes sync2(t).
    }

    // ---- tail: stats of h̃_511 (tag 512, parity 1) -> out[.., 511, ..] ----
    {
        u64 v[8];
        unsigned miss = 0xFFu & ~ownbit;
        while (miss) {
#pragma unroll
            for (int i = 0; i < 8; ++i)
                if (miss & (1u << i)) v[i] = ld_u64g(pol1 + i * 32);
#pragma unroll
            for (int i = 0; i < 8; ++i)
                if ((miss & (1u << i)) && (unsigned)(v[i] >> 32) == 512u)
                    miss &= ~(1u << i);
        }
        v[cb] = (u64)own32;
        float s1 = 0.f, s2 = 0.f;
#pragma unroll
        for (int i = 0; i < 8; ++i) {
            U32H2 hh; hh.u = (unsigned)v[i];
            const float x0 = (float)hh.h[0], x1 = (float)hh.h[1];
            s1 += x0 + x1; s2 += x0 * x0 + x1 * x1;
        }
#pragma unroll
        for (int m = 1; m < 32; m <<= 1) { s1 += __shfl_xor(s1, m); s2 += __shfl_xor(s2, m); }
        const float mu = s1 * (1.f / 512.f);
        const float var = s2 * (1.f / 512.f) - mu * mu;
        const float rs = rsqrtf(fmaxf(var, 0.f) + LN_EPS);
        const size_t orow = (row * 512 + 511) * 512 + col0;
        po[orow]     = (ht0 - mu) * rs * gm0 + bt0;
        po[orow + 1] = (ht1 - mu) * rs * gm1 + bt1;
    }
}

extern "C" void kernel_launch(void* const* d_in, const int* in_sizes, int n_in,
                              void* d_out, int out_size, void* d_ws, size_t ws_size,
                              hipStream_t stream) {
    (void)in_sizes; (void)n_in; (void)out_size; (void)ws_size;
    const float* X     = (const float*)d_in[0];
    const float* Wa    = (const float*)d_in[1];
    const float* Wg    = (const float*)d_in[2];
    const float* ba    = (const float*)d_in[3];
    const float* bg    = (const float*)d_in[4];
    const float* gamma = (const float*)d_in[5];
    const float* beta  = (const float*)d_in[6];
    float* out = (float*)d_out;

    char* ws = (char*)d_ws;
    f16*    Pgh  = (f16*)ws;                      // 67108864 B
    uint4*  WP   = (uint4*)(ws + 67108864);       // 1048576 B
    u64*    THex = (u64*)(ws + 68157440);         // 524288 B (65536 u64)
    float*  Cvec = (float*)(ws + 68681728);       // 8192 B

    init_ex<<<dim3(256), dim3(256), 0, stream>>>(THex, 65536);
    pack_wfrags<<<dim3(256), dim3(256), 0, stream>>>(Wa, Wg, gamma, WP);
    precompute_consts<<<dim3(512), dim3(64), 0, stream>>>(Wa, Wg, gamma, beta, Cvec);
    precompute_gemm<<<dim3(4096), dim3(256), 0, stream>>>(X, Wa, Wg, ba, bg, out, Pgh);

    void* args[] = { (void*)&WP, (void*)&gamma, (void*)&beta, (void*)&Cvec,
                     (void*)&out, (void*)&Pgh, (void*)&THex };
    hipLaunchCooperativeKernel((const void*)scan9, dim3(64), dim3(512),
                               args, 0, stream);
}

// Round 10
// 1677.409 us; speedup vs baseline: 1.3950x; 1.3950x over previous
//
#include <hip/hip_runtime.h>
#include <math.h>

typedef _Float16 f16;
typedef _Float16 f16x8 __attribute__((ext_vector_type(8)));
typedef float f32x4 __attribute__((ext_vector_type(4)));
typedef unsigned long long u64;
typedef unsigned u32;

union U32H2 { unsigned u; f16 h[2]; };
union UV4H8 { uint4 u; f16x8 h; f16 e[8]; };

#define LN_EPS 1e-5f

// ---- cache-bypassing (L3-coherent) 8-byte atomics, relaxed agent scope ----
__device__ __forceinline__ void st_u64g(u64* p, u64 v) {
    __hip_atomic_store(p, v, __ATOMIC_RELAXED, __HIP_MEMORY_SCOPE_AGENT);
}
__device__ __forceinline__ u64 ld_u64g(const u64* p) {
    return __hip_atomic_load(p, __ATOMIC_RELAXED, __HIP_MEMORY_SCOPE_AGENT);
}

// ============================================================================
// init: zero tagged-exchange buffer (every launch — replay safety)
// ============================================================================
__global__ __launch_bounds__(256) void init_ex(u64* p, int n) {
    const int i = blockIdx.x * 256 + threadIdx.x;
    if (i < n) p[i] = 0ull;
}

// ============================================================================
// Phase 0a: pack h-part weights (k<512), GAMMA-FOLDED, into B-fragment order.
//   col = (tile%32)*16 + (lane&15),  k = kf*32 + (lane>>4)*8 + j
// tiles 0..31 = a-gate, 32..63 = g-gate.
// ============================================================================
__global__ __launch_bounds__(256) void pack_wfrags(
    const float* __restrict__ Wa, const float* __restrict__ Wg,
    const float* __restrict__ gamma, uint4* __restrict__ WP)
{
    const int t = blockIdx.x * 256 + threadIdx.x;   // 0..65535
    const int lane = t & 63;
    const int kf = (t >> 6) & 15;
    const int tile = t >> 10;
    const float* W = (tile < 32) ? Wa : Wg;
    const int col = (tile & 31) * 16 + (lane & 15);
    const int k0 = kf * 32 + (lane >> 4) * 8;
    const float* src = W + (size_t)col * 1024 + k0;
    UV4H8 u;
#pragma unroll
    for (int j = 0; j < 8; ++j) u.e[j] = (f16)(src[j] * gamma[k0 + j]);
    WP[t] = u.u;
}

// ============================================================================
// Phase 0a': pack x-part weights (k 512..1023), NO fold, B-fragment order.
// Same tile/lane mapping; k relative to x-part start.
// ============================================================================
__global__ __launch_bounds__(256) void pack_wx(
    const float* __restrict__ Wa, const float* __restrict__ Wg,
    uint4* __restrict__ WPx)
{
    const int t = blockIdx.x * 256 + threadIdx.x;   // 0..65535
    const int lane = t & 63;
    const int kf = (t >> 6) & 15;
    const int tile = t >> 10;
    const float* W = (tile < 32) ? Wa : Wg;
    const int col = (tile & 31) * 16 + (lane & 15);
    const int k0 = kf * 32 + (lane >> 4) * 8;
    const float* src = W + (size_t)col * 1024 + 512 + k0;
    UV4H8 u;
#pragma unroll
    for (int j = 0; j < 8; ++j) u.e[j] = (f16)src[j];
    WPx[t] = u.u;
}

// ============================================================================
// Phase 0b: fold constants:
//   Cvec[0][o]=Wa[o]·beta  Cvec[1][o]=Wa[o]·gamma  Cvec[2][o]=Wg[o]·beta
//   Cvec[3][o]=Wg[o]·gamma   (h-part k<512, fp32)
// ============================================================================
__global__ __launch_bounds__(64) void precompute_consts(
    const float* __restrict__ Wa, const float* __restrict__ Wg,
    const float* __restrict__ gamma, const float* __restrict__ beta,
    float* __restrict__ Cvec)
{
    const int o = blockIdx.x;
    const int l = threadIdx.x;
    const float* wa = Wa + (size_t)o * 1024;
    const float* wg = Wg + (size_t)o * 1024;
    float ca = 0.f, ga = 0.f, cg = 0.f, gg = 0.f;
    for (int k = l; k < 512; k += 64) {
        const float bk = beta[k], gk = gamma[k], a = wa[k], g = wg[k];
        ca += a * bk; ga += a * gk; cg += g * bk; gg += g * gk;
    }
#pragma unroll
    for (int m = 1; m < 64; m <<= 1) {
        ca += __shfl_xor(ca, m); ga += __shfl_xor(ga, m);
        cg += __shfl_xor(cg, m); gg += __shfl_xor(gg, m);
    }
    if (l == 0) {
        Cvec[o] = ca; Cvec[512 + o] = ga; Cvec[1024 + o] = cg; Cvec[1536 + o] = gg;
    }
}

// ============================================================================
// Phase 1: precompute P = X @ Wx^T + bias — f16 MFMA version.
// 4096 blocks x 512 threads; tile M=128, N=128 (8 wave col-tiles of 16).
// tile = bn*8+wv: 0..31 -> Pa (fp32, d_out), 32..63 -> Pg (f16, ws).
// A staged per-64-K-chunk in swizzled LDS (byte ^= (row&7)<<4), f16.
// ============================================================================
__global__ __launch_bounds__(512) void pgemm16(
    const float* __restrict__ X, const uint4* __restrict__ WPx,
    const float* __restrict__ ba, const float* __restrict__ bg,
    float* __restrict__ Pa, f16* __restrict__ Pgh)
{
    __shared__ f16 As[128 * 64];   // 16 KB, swizzled
    const int tid = threadIdx.x;
    const int wv = tid >> 6, lane = tid & 63;
    const int bid = blockIdx.x;
    const int bn = bid & 7;
    const int bm = bid >> 3;
    const int m0 = bm * 128;
    const int tile = bn * 8 + wv;

    // ---- register B-fragments for this wave's 16 cols ----
    f16x8 Bf[16];
#pragma unroll
    for (int kf = 0; kf < 16; ++kf) {
        UV4H8 uu; uu.u = WPx[(size_t)(tile * 16 + kf) * 64 + lane];
        Bf[kf] = uu.h;
    }
    const int tcol = lane & 15;
    const float bias = (tile < 32) ? ba[tile * 16 + tcol]
                                   : bg[(tile - 32) * 16 + tcol];

    f32x4 acc[8];
#pragma unroll
    for (int mt = 0; mt < 8; ++mt) acc[mt] = (f32x4){0.f, 0.f, 0.f, 0.f};

    const int r = tid >> 2;            // staging row 0..127
    const int c16 = (tid & 3) * 16;    // staging col chunk (floats)
    const int swzw = (r & 7) << 4;
    char* wbase = (char*)As + r * 128;
    const int arow = lane & 15;
    const int swzr = (arow & 7) << 4;
    const int hi = (lane >> 4) * 16;   // byte offset within frag row

    for (int kc = 0; kc < 8; ++kc) {
        // ---- stage: 16 f32 -> 16 f16 per thread ----
        {
            const float* src = X + (size_t)(m0 + r) * 512 + kc * 64 + c16;
            const float4 v0 = *(const float4*)(src);
            const float4 v1 = *(const float4*)(src + 4);
            const float4 v2 = *(const float4*)(src + 8);
            const float4 v3 = *(const float4*)(src + 12);
            UV4H8 o0, o1;
            o0.e[0] = (f16)v0.x; o0.e[1] = (f16)v0.y; o0.e[2] = (f16)v0.z; o0.e[3] = (f16)v0.w;
            o0.e[4] = (f16)v1.x; o0.e[5] = (f16)v1.y; o0.e[6] = (f16)v1.z; o0.e[7] = (f16)v1.w;
            o1.e[0] = (f16)v2.x; o1.e[1] = (f16)v2.y; o1.e[2] = (f16)v2.z; o1.e[3] = (f16)v2.w;
            o1.e[4] = (f16)v3.x; o1.e[5] = (f16)v3.y; o1.e[6] = (f16)v3.z; o1.e[7] = (f16)v3.w;
            *(uint4*)(wbase + ((c16 * 2) ^ swzw)) = o0.u;
            *(uint4*)(wbase + ((c16 * 2 + 16) ^ swzw)) = o1.u;
        }
        __syncthreads();
        // ---- compute: 8 m-tiles x 2 kf ----
#pragma unroll
        for (int mt = 0; mt < 8; ++mt) {
            const char* rbase = (const char*)As + (mt * 16 + arow) * 128;
            const f16x8 Af0 = *(const f16x8*)(rbase + ((hi) ^ swzr));
            acc[mt] = __builtin_amdgcn_mfma_f32_16x16x32_f16(Af0, Bf[kc * 2], acc[mt], 0, 0, 0);
            const f16x8 Af1 = *(const f16x8*)(rbase + ((64 + hi) ^ swzr));
            acc[mt] = __builtin_amdgcn_mfma_f32_16x16x32_f16(Af1, Bf[kc * 2 + 1], acc[mt], 0, 0, 0);
        }
        __syncthreads();
    }

    // ---- epilogue: D row = (lane>>4)*4 + i, col = lane&15 ----
    const int drow = (lane >> 4) * 4;
    if (tile < 32) {
        const int col = tile * 16 + tcol;
#pragma unroll
        for (int mt = 0; mt < 8; ++mt)
#pragma unroll
            for (int i = 0; i < 4; ++i)
                Pa[(size_t)(m0 + mt * 16 + drow + i) * 512 + col] = acc[mt][i] + bias;
    } else {
        const int col = (tile - 32) * 16 + tcol;
#pragma unroll
        for (int mt = 0; mt < 8; ++mt)
#pragma unroll
            for (int i = 0; i < 4; ++i)
                Pgh[(size_t)(m0 + mt * 16 + drow + i) * 512 + col] = (f16)(acc[mt][i] + bias);
    }
}

// ============================================================================
// Phase 2: recurrent scan — round-6 arithmetic path (verified absmax 0.03125)
// + own-slot substitution; trailing barrier RESTORED (round-9 removal was -6%).
// Exchange: agent-scope self-tagged u64 = (t+1)<<32 | 2xf16, parity dbuf.
// ============================================================================
__global__ __launch_bounds__(512, 1) void scan10(
    const uint4* __restrict__ WP, const float* __restrict__ gamma,
    const float* __restrict__ beta, const float* __restrict__ Cvec,
    float* po, const f16* __restrict__ Pgh,
    u64* __restrict__ THex)   // [2][8][16][256] tagged
{
    __shared__ f16 hn[16][512];      // raw h̃, XOR-swizzled
    __shared__ float Dx[16][132];    // MFMA D exchange

    const int tid = threadIdx.x;
    const int wv = tid >> 6, lane = tid & 63;
    const int bid = blockIdx.x;
    const int rg = bid >> 3, cb = bid & 7;
    const int c0 = cb * 64, r0 = rg * 16;

    const int tile = (wv < 4) ? (cb * 4 + wv) : (32 + cb * 4 + (wv - 4));
    f16x8 Bf[16];
#pragma unroll
    for (int kf = 0; kf < 16; ++kf) {
        UV4H8 uu; uu.u = WP[(size_t)(tile * 16 + kf) * 64 + lane];
        Bf[kf] = uu.h;
    }

    for (int i = tid; i < 16 * 256; i += 512) ((unsigned*)hn)[i] = 0u;

    const int rb = tid >> 5, u = tid & 31;
    const int col0 = c0 + 2 * u;
    const float Ca0 = Cvec[col0],        Ca1 = Cvec[col0 + 1];
    const float Ga0 = Cvec[512 + col0],  Ga1 = Cvec[512 + col0 + 1];
    const float Cg0 = Cvec[1024 + col0], Cg1 = Cvec[1024 + col0 + 1];
    const float Gg0 = Cvec[1536 + col0], Gg1 = Cvec[1536 + col0 + 1];
    const float gm0 = gamma[col0], gm1 = gamma[col0 + 1];
    const float bt0 = beta[col0],  bt1 = beta[col0 + 1];

    const int arow = lane & 15;
    const int hi16 = (lane >> 4) * 16;
    const int swzr = (arow & 7) << 4;
    const int swzw = (rb & 7) << 4;
    const char* hrow_r = (const char*)&hn[arow][0];
    char* hrow_w = (char*)&hn[rb][0];
    const int dr = (lane >> 4) * 4;
    const int dc = wv * 16 + (lane & 15);
    const size_t row = (size_t)(r0 + rb);

    u64* pub0 = THex + ((size_t)0 * 8 + rg) * 4096 + (size_t)rb * 256 + cb * 32 + u;
    u64* pub1 = THex + ((size_t)1 * 8 + rg) * 4096 + (size_t)rb * 256 + cb * 32 + u;
    const u64* pol0 = THex + ((size_t)0 * 8 + rg) * 4096 + (size_t)rb * 256 + u;
    const u64* pol1 = THex + ((size_t)1 * 8 + rg) * 4096 + (size_t)rb * 256 + u;
    const unsigned ownbit = 1u << cb;

    float ht0, ht1;
    u32 own32;
    // ---- t = 0 ----
    {
        const size_t orow = (row * 512 + 0) * 512 + col0;
        const float2 pa = *(const float2*)(po + orow);
        U32H2 pg; pg.u = *(const unsigned*)(Pgh + orow);
        const float a0 = pa.x, a1 = pa.y;
        const float g0 = (float)pg.h[0], g1 = (float)pg.h[1];
        const float al0 = 1.f / (1.f + __expf(-g0));
        const float al1 = 1.f / (1.f + __expf(-g1));
        const float ac0 = fminf(fmaxf(a0, -15.f), 15.f);
        const float ac1 = fminf(fmaxf(a1, -15.f), 15.f);
        const float e0 = __expf(2.f * ac0), e1 = __expf(2.f * ac1);
        const float th0 = (e0 - 1.f) / (e0 + 1.f);
        const float th1 = (e1 - 1.f) / (e1 + 1.f);
        ht0 = al0 * (th0 - a0) + a0;
        ht1 = al1 * (th1 - a1) + a1;
        U32H2 hw; hw.h[0] = (f16)ht0; hw.h[1] = (f16)ht1;
        own32 = hw.u;
        st_u64g(pub0, ((u64)1u << 32) | (u64)own32);
    }

    for (int t = 1; t < 512; ++t) {
        const unsigned tg = (unsigned)t;
        const u64* hp = ((t - 1) & 1) ? pol1 : pol0;
        const size_t orow = (row * 512 + (size_t)t) * 512 + col0;
        const float2 pa = *(const float2*)(po + orow);
        U32H2 pg; pg.u = *(const unsigned*)(Pgh + orow);

        // ---- poll 7 remote chunks (own slice from regs) ----
        u64 v[8];
        unsigned miss = 0xFFu & ~ownbit;
        while (miss) {
#pragma unroll
            for (int i = 0; i < 8; ++i)
                if (miss & (1u << i)) v[i] = ld_u64g(hp + i * 32);
#pragma unroll
            for (int i = 0; i < 8; ++i)
                if ((miss & (1u << i)) && (unsigned)(v[i] >> 32) == tg)
                    miss &= ~(1u << i);
        }
        v[cb] = (u64)own32;

        // ---- local LN stats + swizzled LDS rebuild ----
        float s1 = 0.f, s2 = 0.f;
#pragma unroll
        for (int i = 0; i < 8; ++i) {
            U32H2 hh; hh.u = (unsigned)v[i];
            const float x0 = (float)hh.h[0], x1 = (float)hh.h[1];
            s1 += x0 + x1; s2 += x0 * x0 + x1 * x1;
            *(u32*)(hrow_w + ((128 * i + 4 * u) ^ swzw)) = (unsigned)v[i];
        }
#pragma unroll
        for (int m = 1; m < 32; m <<= 1) { s1 += __shfl_xor(s1, m); s2 += __shfl_xor(s2, m); }
        const float mu = s1 * (1.f / 512.f);
        const float var = s2 * (1.f / 512.f) - mu * mu;
        const float rs = rsqrtf(fmaxf(var, 0.f) + LN_EPS);
        const float murs = mu * rs;
        __syncthreads();   // sync1: hn rebuilt

        // ---- MFMA (round-6 exact) ----
        f32x4 acc0 = {0.f, 0.f, 0.f, 0.f};
        f32x4 acc1 = {0.f, 0.f, 0.f, 0.f};
#pragma unroll
        for (int kf = 0; kf < 8; ++kf) {
            const f16x8 Af0 = *(const f16x8*)(hrow_r + ((kf * 64 + hi16) ^ swzr));
            acc0 = __builtin_amdgcn_mfma_f32_16x16x32_f16(Af0, Bf[kf], acc0, 0, 0, 0);
            const f16x8 Af1 = *(const f16x8*)(hrow_r + (((kf + 8) * 64 + hi16) ^ swzr));
            acc1 = __builtin_amdgcn_mfma_f32_16x16x32_f16(Af1, Bf[kf + 8], acc1, 0, 0, 0);
        }
        Dx[dr + 0][dc] = acc0[0] + acc1[0];
        Dx[dr + 1][dc] = acc0[1] + acc1[1];
        Dx[dr + 2][dc] = acc0[2] + acc1[2];
        Dx[dr + 3][dc] = acc0[3] + acc1[3];
        __syncthreads();   // sync2: Dx ready

        // ---- scalar LN correction + gated blend (round-6 exact) ----
        const float a0 = rs * Dx[rb][2 * u]          - murs * Ga0 + Ca0 + pa.x;
        const float a1 = rs * Dx[rb][2 * u + 1]      - murs * Ga1 + Ca1 + pa.y;
        const float g0 = rs * Dx[rb][64 + 2 * u]     - murs * Gg0 + Cg0 + (float)pg.h[0];
        const float g1 = rs * Dx[rb][64 + 2 * u + 1] - murs * Gg1 + Cg1 + (float)pg.h[1];
        const float al0 = 1.f / (1.f + __expf(-g0));
        const float al1 = 1.f / (1.f + __expf(-g1));
        const float ac0 = fminf(fmaxf(a0, -15.f), 15.f);
        const float ac1 = fminf(fmaxf(a1, -15.f), 15.f);
        const float e0 = __expf(2.f * ac0), e1 = __expf(2.f * ac1);
        const float th0 = (e0 - 1.f) / (e0 + 1.f);
        const float th1 = (e1 - 1.f) / (e1 + 1.f);
        const float nt0 = al0 * (th0 - a0) + a0;
        const float nt1 = al1 * (th1 - a1) + a1;

        // ---- publish h̃_t FIRST ----
        {
            U32H2 hw; hw.h[0] = (f16)nt0; hw.h[1] = (f16)nt1;
            st_u64g((t & 1) ? pub1 : pub0,
                    ((u64)(unsigned)(t + 1) << 32) | (u64)hw.u);
            po[orow - 512]     = (ht0 - mu) * rs * gm0 + bt0;
            po[orow - 512 + 1] = (ht1 - mu) * rs * gm1 + bt1;
            ht0 = nt0; ht1 = nt1; own32 = hw.u;
        }
        __syncthreads();   // sync3 restored (round-9 removal cost ~6%)
    }

    // ---- tail: out[.., 511, ..] ----
    {
        u64 v[8];
        unsigned miss = 0xFFu & ~ownbit;
        while (miss) {
#pragma unroll
            for (int i = 0; i < 8; ++i)
                if (miss & (1u << i)) v[i] = ld_u64g(pol1 + i * 32);
#pragma unroll
            for (int i = 0; i < 8; ++i)
                if ((miss & (1u << i)) && (unsigned)(v[i] >> 32) == 512u)
                    miss &= ~(1u << i);
        }
        v[cb] = (u64)own32;
        float s1 = 0.f, s2 = 0.f;
#pragma unroll
        for (int i = 0; i < 8; ++i) {
            U32H2 hh; hh.u = (unsigned)v[i];
            const float x0 = (float)hh.h[0], x1 = (float)hh.h[1];
            s1 += x0 + x1; s2 += x0 * x0 + x1 * x1;
        }
#pragma unroll
        for (int m = 1; m < 32; m <<= 1) { s1 += __shfl_xor(s1, m); s2 += __shfl_xor(s2, m); }
        const float mu = s1 * (1.f / 512.f);
        const float var = s2 * (1.f / 512.f) - mu * mu;
        const float rs = rsqrtf(fmaxf(var, 0.f) + LN_EPS);
        const size_t orow = (row * 512 + 511) * 512 + col0;
        po[orow]     = (ht0 - mu) * rs * gm0 + bt0;
        po[orow + 1] = (ht1 - mu) * rs * gm1 + bt1;
    }
}

extern "C" void kernel_launch(void* const* d_in, const int* in_sizes, int n_in,
                              void* d_out, int out_size, void* d_ws, size_t ws_size,
                              hipStream_t stream) {
    (void)in_sizes; (void)n_in; (void)out_size; (void)ws_size;
    const float* X     = (const float*)d_in[0];
    const float* Wa    = (const float*)d_in[1];
    const float* Wg    = (const float*)d_in[2];
    const float* ba    = (const float*)d_in[3];
    const float* bg    = (const float*)d_in[4];
    const float* gamma = (const float*)d_in[5];
    const float* beta  = (const float*)d_in[6];
    float* out = (float*)d_out;

    char* ws = (char*)d_ws;
    f16*    Pgh  = (f16*)ws;                      // 67108864 B
    uint4*  WP   = (uint4*)(ws + 67108864);       // 1048576 B
    u64*    THex = (u64*)(ws + 68157440);         // 524288 B
    float*  Cvec = (float*)(ws + 68681728);       // 8192 B
    uint4*  WPx  = (uint4*)(ws + 68689920);       // 1048576 B

    init_ex<<<dim3(256), dim3(256), 0, stream>>>(THex, 65536);
    pack_wfrags<<<dim3(256), dim3(256), 0, stream>>>(Wa, Wg, gamma, WP);
    pack_wx<<<dim3(256), dim3(256), 0, stream>>>(Wa, Wg, WPx);
    precompute_consts<<<dim3(512), dim3(64), 0, stream>>>(Wa, Wg, gamma, beta, Cvec);
    pgemm16<<<dim3(4096), dim3(512), 0, stream>>>(X, WPx, ba, bg, out, Pgh);

    void* args[] = { (void*)&WP, (void*)&gamma, (void*)&beta, (void*)&Cvec,
                     (void*)&out, (void*)&Pgh, (void*)&THex };
    hipLaunchCooperativeKernel((const void*)scan10, dim3(64), dim3(512),
                               args, 0, stream);
}

// Round 11
// 1499.528 us; speedup vs baseline: 1.5605x; 1.1186x over previous
//
#include <hip/hip_runtime.h>
#include <math.h>

typedef _Float16 f16;
typedef _Float16 f16x8 __attribute__((ext_vector_type(8)));
typedef float f32x4 __attribute__((ext_vector_type(4)));
typedef unsigned long long u64;
typedef unsigned u32;

union U32H2 { unsigned u; f16 h[2]; };
union UV4H8 { uint4 u; f16x8 h; f16 e[8]; };

#define LN_EPS 1e-5f

// ---- cache-bypassing (L3-coherent) 8-byte atomics, relaxed agent scope ----
__device__ __forceinline__ void st_u64g(u64* p, u64 v) {
    __hip_atomic_store(p, v, __ATOMIC_RELAXED, __HIP_MEMORY_SCOPE_AGENT);
}
__device__ __forceinline__ u64 ld_u64g(const u64* p) {
    return __hip_atomic_load(p, __ATOMIC_RELAXED, __HIP_MEMORY_SCOPE_AGENT);
}

// ============================================================================
// init: zero tagged-exchange buffer (every launch — replay safety)
// ============================================================================
__global__ __launch_bounds__(256) void init_ex(u64* p, int n) {
    const int i = blockIdx.x * 256 + threadIdx.x;
    if (i < n) p[i] = 0ull;
}

// ============================================================================
// Phase 0a: pack h-part weights (k<512), GAMMA-FOLDED, into B-fragment order.
//   col = (tile%32)*16 + (lane&15),  k = kf*32 + (lane>>4)*8 + j
// tiles 0..31 = a-gate, 32..63 = g-gate.
// ============================================================================
__global__ __launch_bounds__(256) void pack_wfrags(
    const float* __restrict__ Wa, const float* __restrict__ Wg,
    const float* __restrict__ gamma, uint4* __restrict__ WP)
{
    const int t = blockIdx.x * 256 + threadIdx.x;   // 0..65535
    const int lane = t & 63;
    const int kf = (t >> 6) & 15;
    const int tile = t >> 10;
    const float* W = (tile < 32) ? Wa : Wg;
    const int col = (tile & 31) * 16 + (lane & 15);
    const int k0 = kf * 32 + (lane >> 4) * 8;
    const float* src = W + (size_t)col * 1024 + k0;
    UV4H8 u;
#pragma unroll
    for (int j = 0; j < 8; ++j) u.e[j] = (f16)(src[j] * gamma[k0 + j]);
    WP[t] = u.u;
}

// ============================================================================
// Phase 0a': pack x-part weights (k 512..1023), NO fold, B-fragment order.
// ============================================================================
__global__ __launch_bounds__(256) void pack_wx(
    const float* __restrict__ Wa, const float* __restrict__ Wg,
    uint4* __restrict__ WPx)
{
    const int t = blockIdx.x * 256 + threadIdx.x;   // 0..65535
    const int lane = t & 63;
    const int kf = (t >> 6) & 15;
    const int tile = t >> 10;
    const float* W = (tile < 32) ? Wa : Wg;
    const int col = (tile & 31) * 16 + (lane & 15);
    const int k0 = kf * 32 + (lane >> 4) * 8;
    const float* src = W + (size_t)col * 1024 + 512 + k0;
    UV4H8 u;
#pragma unroll
    for (int j = 0; j < 8; ++j) u.e[j] = (f16)src[j];
    WPx[t] = u.u;
}

// ============================================================================
// Phase 0b: fold constants:
//   Cvec[0][o]=Wa[o]·beta  Cvec[1][o]=Wa[o]·gamma  Cvec[2][o]=Wg[o]·beta
//   Cvec[3][o]=Wg[o]·gamma   (h-part k<512, fp32)
// ============================================================================
__global__ __launch_bounds__(64) void precompute_consts(
    const float* __restrict__ Wa, const float* __restrict__ Wg,
    const float* __restrict__ gamma, const float* __restrict__ beta,
    float* __restrict__ Cvec)
{
    const int o = blockIdx.x;
    const int l = threadIdx.x;
    const float* wa = Wa + (size_t)o * 1024;
    const float* wg = Wg + (size_t)o * 1024;
    float ca = 0.f, ga = 0.f, cg = 0.f, gg = 0.f;
    for (int k = l; k < 512; k += 64) {
        const float bk = beta[k], gk = gamma[k], a = wa[k], g = wg[k];
        ca += a * bk; ga += a * gk; cg += g * bk; gg += g * gk;
    }
#pragma unroll
    for (int m = 1; m < 64; m <<= 1) {
        ca += __shfl_xor(ca, m); ga += __shfl_xor(ga, m);
        cg += __shfl_xor(cg, m); gg += __shfl_xor(gg, m);
    }
    if (l == 0) {
        Cvec[o] = ca; Cvec[512 + o] = ga; Cvec[1024 + o] = cg; Cvec[1536 + o] = gg;
    }
}

// ============================================================================
// Phase 1: precompute P = X @ Wx^T + bias — f16 MFMA (verified round 10).
// ============================================================================
__global__ __launch_bounds__(512) void pgemm16(
    const float* __restrict__ X, const uint4* __restrict__ WPx,
    const float* __restrict__ ba, const float* __restrict__ bg,
    float* __restrict__ Pa, f16* __restrict__ Pgh)
{
    __shared__ f16 As[128 * 64];   // 16 KB, swizzled
    const int tid = threadIdx.x;
    const int wv = tid >> 6, lane = tid & 63;
    const int bid = blockIdx.x;
    const int bn = bid & 7;
    const int bm = bid >> 3;
    const int m0 = bm * 128;
    const int tile = bn * 8 + wv;

    f16x8 Bf[16];
#pragma unroll
    for (int kf = 0; kf < 16; ++kf) {
        UV4H8 uu; uu.u = WPx[(size_t)(tile * 16 + kf) * 64 + lane];
        Bf[kf] = uu.h;
    }
    const int tcol = lane & 15;
    const float bias = (tile < 32) ? ba[tile * 16 + tcol]
                                   : bg[(tile - 32) * 16 + tcol];

    f32x4 acc[8];
#pragma unroll
    for (int mt = 0; mt < 8; ++mt) acc[mt] = (f32x4){0.f, 0.f, 0.f, 0.f};

    const int r = tid >> 2;
    const int c16 = (tid & 3) * 16;
    const int swzw = (r & 7) << 4;
    char* wbase = (char*)As + r * 128;
    const int arow = lane & 15;
    const int swzr = (arow & 7) << 4;
    const int hi = (lane >> 4) * 16;

    for (int kc = 0; kc < 8; ++kc) {
        {
            const float* src = X + (size_t)(m0 + r) * 512 + kc * 64 + c16;
            const float4 v0 = *(const float4*)(src);
            const float4 v1 = *(const float4*)(src + 4);
            const float4 v2 = *(const float4*)(src + 8);
            const float4 v3 = *(const float4*)(src + 12);
            UV4H8 o0, o1;
            o0.e[0] = (f16)v0.x; o0.e[1] = (f16)v0.y; o0.e[2] = (f16)v0.z; o0.e[3] = (f16)v0.w;
            o0.e[4] = (f16)v1.x; o0.e[5] = (f16)v1.y; o0.e[6] = (f16)v1.z; o0.e[7] = (f16)v1.w;
            o1.e[0] = (f16)v2.x; o1.e[1] = (f16)v2.y; o1.e[2] = (f16)v2.z; o1.e[3] = (f16)v2.w;
            o1.e[4] = (f16)v3.x; o1.e[5] = (f16)v3.y; o1.e[6] = (f16)v3.z; o1.e[7] = (f16)v3.w;
            *(uint4*)(wbase + ((c16 * 2) ^ swzw)) = o0.u;
            *(uint4*)(wbase + ((c16 * 2 + 16) ^ swzw)) = o1.u;
        }
        __syncthreads();
#pragma unroll
        for (int mt = 0; mt < 8; ++mt) {
            const char* rbase = (const char*)As + (mt * 16 + arow) * 128;
            const f16x8 Af0 = *(const f16x8*)(rbase + ((hi) ^ swzr));
            acc[mt] = __builtin_amdgcn_mfma_f32_16x16x32_f16(Af0, Bf[kc * 2], acc[mt], 0, 0, 0);
            const f16x8 Af1 = *(const f16x8*)(rbase + ((64 + hi) ^ swzr));
            acc[mt] = __builtin_amdgcn_mfma_f32_16x16x32_f16(Af1, Bf[kc * 2 + 1], acc[mt], 0, 0, 0);
        }
        __syncthreads();
    }

    const int drow = (lane >> 4) * 4;
    if (tile < 32) {
        const int col = tile * 16 + tcol;
#pragma unroll
        for (int mt = 0; mt < 8; ++mt)
#pragma unroll
            for (int i = 0; i < 4; ++i)
                Pa[(size_t)(m0 + mt * 16 + drow + i) * 512 + col] = acc[mt][i] + bias;
    } else {
        const int col = (tile - 32) * 16 + tcol;
#pragma unroll
        for (int mt = 0; mt < 8; ++mt)
#pragma unroll
            for (int i = 0; i < 4; ++i)
                Pgh[(size_t)(m0 + mt * 16 + drow + i) * 512 + col] = (f16)(acc[mt][i] + bias);
    }
}

// ============================================================================
// Phase 2: recurrent scan — round-6 structure VERBATIM (branchless all-8 poll,
// no own-slot skip, trailing barrier) with ONE change: the stats shfl_xor
// chain moved AFTER sync1 so it overlaps the MFMA phase (consumers of mu/rs
// all run after sync2). Arithmetic identical (absmax 0.03125 path).
// ============================================================================
__global__ __launch_bounds__(512, 1) void scan11(
    const uint4* __restrict__ WP, const float* __restrict__ gamma,
    const float* __restrict__ beta, const float* __restrict__ Cvec,
    float* po, const f16* __restrict__ Pgh,
    u64* __restrict__ THex)   // [2][8][16][256] tagged (t+1)<<32 | 2xf16
{
    __shared__ f16 hn[16][512];      // raw h̃, XOR-swizzled
    __shared__ float Dx[16][132];    // MFMA D exchange

    const int tid = threadIdx.x;
    const int wv = tid >> 6, lane = tid & 63;
    const int bid = blockIdx.x;
    const int rg = bid >> 3, cb = bid & 7;
    const int c0 = cb * 64, r0 = rg * 16;

    const int tile = (wv < 4) ? (cb * 4 + wv) : (32 + cb * 4 + (wv - 4));
    f16x8 Bf[16];
#pragma unroll
    for (int kf = 0; kf < 16; ++kf) {
        UV4H8 uu; uu.u = WP[(size_t)(tile * 16 + kf) * 64 + lane];
        Bf[kf] = uu.h;
    }

    for (int i = tid; i < 16 * 256; i += 512) ((unsigned*)hn)[i] = 0u;

    const int rb = tid >> 5, u = tid & 31;
    const int col0 = c0 + 2 * u;
    const float Ca0 = Cvec[col0],        Ca1 = Cvec[col0 + 1];
    const float Ga0 = Cvec[512 + col0],  Ga1 = Cvec[512 + col0 + 1];
    const float Cg0 = Cvec[1024 + col0], Cg1 = Cvec[1024 + col0 + 1];
    const float Gg0 = Cvec[1536 + col0], Gg1 = Cvec[1536 + col0 + 1];
    const float gm0 = gamma[col0], gm1 = gamma[col0 + 1];
    const float bt0 = beta[col0],  bt1 = beta[col0 + 1];

    const int arow = lane & 15;
    const int hi16 = (lane >> 4) * 16;
    const int swzr = (arow & 7) << 4;
    const int swzw = (rb & 7) << 4;
    const char* hrow_r = (const char*)&hn[arow][0];
    char* hrow_w = (char*)&hn[rb][0];
    const int dr = (lane >> 4) * 4;
    const int dc = wv * 16 + (lane & 15);
    const size_t row = (size_t)(r0 + rb);

    u64* pub0 = THex + ((size_t)0 * 8 + rg) * 4096 + (size_t)rb * 256 + cb * 32 + u;
    u64* pub1 = THex + ((size_t)1 * 8 + rg) * 4096 + (size_t)rb * 256 + cb * 32 + u;
    const u64* pol0 = THex + ((size_t)0 * 8 + rg) * 4096 + (size_t)rb * 256 + u;
    const u64* pol1 = THex + ((size_t)1 * 8 + rg) * 4096 + (size_t)rb * 256 + u;

    float ht0, ht1;
    // ---- t = 0 ----
    {
        const size_t orow = (row * 512 + 0) * 512 + col0;
        const float2 pa = *(const float2*)(po + orow);
        U32H2 pg; pg.u = *(const unsigned*)(Pgh + orow);
        const float a0 = pa.x, a1 = pa.y;
        const float g0 = (float)pg.h[0], g1 = (float)pg.h[1];
        const float al0 = 1.f / (1.f + __expf(-g0));
        const float al1 = 1.f / (1.f + __expf(-g1));
        const float ac0 = fminf(fmaxf(a0, -15.f), 15.f);
        const float ac1 = fminf(fmaxf(a1, -15.f), 15.f);
        const float e0 = __expf(2.f * ac0), e1 = __expf(2.f * ac1);
        const float th0 = (e0 - 1.f) / (e0 + 1.f);
        const float th1 = (e1 - 1.f) / (e1 + 1.f);
        ht0 = al0 * (th0 - a0) + a0;
        ht1 = al1 * (th1 - a1) + a1;
        U32H2 hw; hw.h[0] = (f16)ht0; hw.h[1] = (f16)ht1;
        st_u64g(pub0, ((u64)1u << 32) | (u64)hw.u);
    }

    for (int t = 1; t < 512; ++t) {
        const unsigned tg = (unsigned)t;
        const u64* hp = ((t - 1) & 1) ? pol1 : pol0;
        const size_t orow = (row * 512 + (size_t)t) * 512 + col0;
        const float2 pa = *(const float2*)(po + orow);
        U32H2 pg; pg.u = *(const unsigned*)(Pgh + orow);

        // ---- branchless coalesced poll: all 8 u64 every iteration ----
        u64 v[8];
        for (;;) {
#pragma unroll
            for (int i = 0; i < 8; ++i) v[i] = ld_u64g(hp + i * 32);
            bool ok = true;
#pragma unroll
            for (int i = 0; i < 8; ++i) ok &= ((unsigned)(v[i] >> 32) == tg);
            if (ok) break;
        }

        // ---- per-thread stats partials + swizzled LDS rebuild ----
        float s1 = 0.f, s2 = 0.f;
#pragma unroll
        for (int i = 0; i < 8; ++i) {
            U32H2 hh; hh.u = (unsigned)v[i];
            const float x0 = (float)hh.h[0], x1 = (float)hh.h[1];
            s1 += x0 + x1; s2 += x0 * x0 + x1 * x1;
            *(u32*)(hrow_w + ((128 * i + 4 * u) ^ swzw)) = (unsigned)v[i];
        }
        __syncthreads();   // sync1: hn rebuilt

        // ---- stats shfl chain AFTER sync1: overlaps the MFMA phase ----
#pragma unroll
        for (int m = 1; m < 32; m <<= 1) { s1 += __shfl_xor(s1, m); s2 += __shfl_xor(s2, m); }
        const float mu = s1 * (1.f / 512.f);
        const float var = s2 * (1.f / 512.f) - mu * mu;
        const float rs = rsqrtf(fmaxf(var, 0.f) + LN_EPS);
        const float murs = mu * rs;

        // ---- MFMA (round-6 exact) ----
        f32x4 acc0 = {0.f, 0.f, 0.f, 0.f};
        f32x4 acc1 = {0.f, 0.f, 0.f, 0.f};
#pragma unroll
        for (int kf = 0; kf < 8; ++kf) {
            const f16x8 Af0 = *(const f16x8*)(hrow_r + ((kf * 64 + hi16) ^ swzr));
            acc0 = __builtin_amdgcn_mfma_f32_16x16x32_f16(Af0, Bf[kf], acc0, 0, 0, 0);
            const f16x8 Af1 = *(const f16x8*)(hrow_r + (((kf + 8) * 64 + hi16) ^ swzr));
            acc1 = __builtin_amdgcn_mfma_f32_16x16x32_f16(Af1, Bf[kf + 8], acc1, 0, 0, 0);
        }
        Dx[dr + 0][dc] = acc0[0] + acc1[0];
        Dx[dr + 1][dc] = acc0[1] + acc1[1];
        Dx[dr + 2][dc] = acc0[2] + acc1[2];
        Dx[dr + 3][dc] = acc0[3] + acc1[3];
        __syncthreads();   // sync2: Dx ready

        // ---- scalar LN correction + gated blend (round-6 exact) ----
        const float a0 = rs * Dx[rb][2 * u]          - murs * Ga0 + Ca0 + pa.x;
        const float a1 = rs * Dx[rb][2 * u + 1]      - murs * Ga1 + Ca1 + pa.y;
        const float g0 = rs * Dx[rb][64 + 2 * u]     - murs * Gg0 + Cg0 + (float)pg.h[0];
        const float g1 = rs * Dx[rb][64 + 2 * u + 1] - murs * Gg1 + Cg1 + (float)pg.h[1];
        const float al0 = 1.f / (1.f + __expf(-g0));
        const float al1 = 1.f / (1.f + __expf(-g1));
        const float ac0 = fminf(fmaxf(a0, -15.f), 15.f);
        const float ac1 = fminf(fmaxf(a1, -15.f), 15.f);
        const float e0 = __expf(2.f * ac0), e1 = __expf(2.f * ac1);
        const float th0 = (e0 - 1.f) / (e0 + 1.f);
        const float th1 = (e1 - 1.f) / (e1 + 1.f);
        const float nt0 = al0 * (th0 - a0) + a0;
        const float nt1 = al1 * (th1 - a1) + a1;

        // ---- publish h̃_t FIRST (consumers' critical path) ----
        {
            U32H2 hw; hw.h[0] = (f16)nt0; hw.h[1] = (f16)nt1;
            st_u64g((t & 1) ? pub1 : pub0,
                    ((u64)(unsigned)(t + 1) << 32) | (u64)hw.u);
            po[orow - 512]     = (ht0 - mu) * rs * gm0 + bt0;
            po[orow - 512 + 1] = (ht1 - mu) * rs * gm1 + bt1;
            ht0 = nt0; ht1 = nt1;
        }
        __syncthreads();   // sync3 (round-6 proven)
    }

    // ---- tail: out[.., 511, ..] ----
    {
        u64 v[8];
        for (;;) {
#pragma unroll
            for (int i = 0; i < 8; ++i) v[i] = ld_u64g(pol1 + i * 32);
            bool ok = true;
#pragma unroll
            for (int i = 0; i < 8; ++i) ok &= ((unsigned)(v[i] >> 32) == 512u);
            if (ok) break;
        }
        float s1 = 0.f, s2 = 0.f;
#pragma unroll
        for (int i = 0; i < 8; ++i) {
            U32H2 hh; hh.u = (unsigned)v[i];
            const float x0 = (float)hh.h[0], x1 = (float)hh.h[1];
            s1 += x0 + x1; s2 += x0 * x0 + x1 * x1;
        }
#pragma unroll
        for (int m = 1; m < 32; m <<= 1) { s1 += __shfl_xor(s1, m); s2 += __shfl_xor(s2, m); }
        const float mu = s1 * (1.f / 512.f);
        const float var = s2 * (1.f / 512.f) - mu * mu;
        const float rs = rsqrtf(fmaxf(var, 0.f) + LN_EPS);
        const size_t orow = (row * 512 + 511) * 512 + col0;
        po[orow]     = (ht0 - mu) * rs * gm0 + bt0;
        po[orow + 1] = (ht1 - mu) * rs * gm1 + bt1;
    }
}

extern "C" void kernel_launch(void* const* d_in, const int* in_sizes, int n_in,
                              void* d_out, int out_size, void* d_ws, size_t ws_size,
                              hipStream_t stream) {
    (void)in_sizes; (void)n_in; (void)out_size; (void)ws_size;
    const float* X     = (const float*)d_in[0];
    const float* Wa    = (const float*)d_in[1];
    const float* Wg    = (const float*)d_in[2];
    const float* ba    = (const float*)d_in[3];
    const float* bg    = (const float*)d_in[4];
    const float* gamma = (const float*)d_in[5];
    const float* beta  = (const float*)d_in[6];
    float* out = (float*)d_out;

    char* ws = (char*)d_ws;
    f16*    Pgh  = (f16*)ws;                      // 67108864 B
    uint4*  WP   = (uint4*)(ws + 67108864);       // 1048576 B
    u64*    THex = (u64*)(ws + 68157440);         // 524288 B
    float*  Cvec = (float*)(ws + 68681728);       // 8192 B
    uint4*  WPx  = (uint4*)(ws + 68689920);       // 1048576 B

    init_ex<<<dim3(256), dim3(256), 0, stream>>>(THex, 65536);
    pack_wfrags<<<dim3(256), dim3(256), 0, stream>>>(Wa, Wg, gamma, WP);
    pack_wx<<<dim3(256), dim3(256), 0, stream>>>(Wa, Wg, WPx);
    precompute_consts<<<dim3(512), dim3(64), 0, stream>>>(Wa, Wg, gamma, beta, Cvec);
    pgemm16<<<dim3(4096), dim3(512), 0, stream>>>(X, WPx, ba, bg, out, Pgh);

    void* args[] = { (void*)&WP, (void*)&gamma, (void*)&beta, (void*)&Cvec,
                     (void*)&out, (void*)&Pgh, (void*)&THex };
    hipLaunchCooperativeKernel((const void*)scan11, dim3(64), dim3(512),
                               args, 0, stream);
}